// Round 5
// baseline (241.485 us; speedup 1.0000x reference)
//
#include <hip/hip_runtime.h>
#include <stdint.h>

#define B_ 32
#define T_ 32
#define NPIX 784
#define NFRM 1024
#define EPSV 1e-3f

typedef __attribute__((ext_vector_type(8))) _Float16 half8v;
typedef __attribute__((ext_vector_type(4))) float float4v;

// ---- LDS map (bytes) ----
// act region [0, 75456)       : fp16 acts, 6 cb * 12576 B; chunk = (cb, pixel) 16B
// zero page  [75456, 75472)
// x region   [75472, 78608)   : raw frame fp32 (784*4)
#define CB_STRIDE 12576
#define ZERO_OFF  75456
#define X_OFF     75472
#define LDS_TOT   78608              // <= 81920 -> 2 blocks/CU
#define WPACK     43008              // bytes per conv weight pack

__device__ __forceinline__ unsigned short f2h(float f) {
    union { _Float16 h; unsigned short u; } cv; cv.h = (_Float16)f; return cv.u;
}

// ---------------------------------------------------------------------------
// Kernel 0: pack w2/w3 as fp16 in MFMA-B fragment order [s][q][co][j].
// k = s*32 + q*8 + j = tap*48 + cin ; k >= 432 zero-padded.
// ---------------------------------------------------------------------------
__global__ __launch_bounds__(256) void pack_weights(
    const float* __restrict__ w2, const float* __restrict__ w3,
    unsigned short* __restrict__ out)
{
    int idx = blockIdx.x * 256 + threadIdx.x;     // 0 .. 43007
    int conv = idx / 21504;
    int r = idx - conv * 21504;
    const float* w = conv ? w3 : w2;
    int s  = r / 1536;
    int r2 = r - s * 1536;
    int q  = r2 / 384;
    int r3 = r2 - q * 384;
    int co = r3 >> 3, j = r3 & 7;
    int k  = s * 32 + q * 8 + j;
    unsigned short v = 0;
    if (k < 432) v = f2h(w[k * 48 + co]);
    out[idx] = v;
}

// ---------------------------------------------------------------------------
// Fused conv1 + conv2 + conv3 (fp16 MFMA) + ReLU + avgpool + BN1.
// One block = one frame; 512 threads = 8 waves; wave w owns M-tiles tt=w+8*mt.
// B-operand fragments load straight from global (L1/L2-hot, same for all blocks).
// mt=6 (tiles 48..55) is real only for wave 0 -> other waves branch over it.
// ---------------------------------------------------------------------------
#define KLOOP(GW)                                                              \
    _Pragma("unroll")                                                          \
    for (int s = 0; s < 14; ++s) {                                             \
        const char* wb = (GW) + bB + s * 3072;                                 \
        half8v bv0 = *(const half8v*)(wb);                                     \
        half8v bv1 = *(const half8v*)(wb + 256);                               \
        half8v bv2 = *(const half8v*)(wb + 512);                               \
        _Pragma("unroll")                                                      \
        for (int mt = 0; mt < 7; ++mt) {                                       \
            if (mt < 6 || wid == 0) {                                          \
                int ad = pixb16[mt] + aoff_s[s];                               \
                ad = ((msk[mt] >> tap_s[s]) & 1) ? ad : ZERO_OFF;              \
                half8v a = *(const half8v*)(smem + ad);                        \
                acc[mt][0] = __builtin_amdgcn_mfma_f32_16x16x32_f16(a, bv0, acc[mt][0], 0, 0, 0); \
                acc[mt][1] = __builtin_amdgcn_mfma_f32_16x16x32_f16(a, bv1, acc[mt][1], 0, 0, 0); \
                acc[mt][2] = __builtin_amdgcn_mfma_f32_16x16x32_f16(a, bv2, acc[mt][2], 0, 0, 0); \
            }                                                                  \
        }                                                                      \
    }

__global__ __launch_bounds__(512, 4) void fused_cnn(
    const float* __restrict__ x,              // [NFRM][784] fp32
    const float* __restrict__ w1, const float* __restrict__ b1,
    const float* __restrict__ b2, const float* __restrict__ b3,
    const unsigned short* __restrict__ wpack, // [2][21504] halfs (frag order)
    float* __restrict__ feats,                // [NFRM][48]
    const float* __restrict__ bn_g, const float* __restrict__ bn_b,
    const float* __restrict__ bn_m, const float* __restrict__ bn_v)
{
    __shared__ __align__(16) char smem[LDS_TOT];
    const int tid = threadIdx.x;
    const int n = blockIdx.x;
    const int lane = tid & 63, wid = tid >> 6;
    const int l15 = lane & 15, q = lane >> 4;

    // zero page + stage raw frame
    if (tid < 4) *(unsigned int*)(smem + ZERO_OFF + tid * 4) = 0;
    {
        const float* xf = x + (size_t)n * NPIX;
        float* sx = (float*)(smem + X_OFF);
        for (int i = tid; i < NPIX; i += 512) sx[i] = xf[i];
    }
    __syncthreads();

    // ---- conv1 (1->48) on VALU, fp16 chunks into act region ----
    {
        const float* sx = (const float*)(smem + X_OFF);
        for (int rnd = 0; rnd < 2; ++rnd) {
            int p = tid + rnd * 512;
            if (p < NPIX) {
                int y = p / 28, xx = p % 28;
                float a[48];
                #pragma unroll
                for (int c = 0; c < 48; ++c) a[c] = b1[c];
                #pragma unroll
                for (int dy = 0; dy < 3; ++dy) {
                    int yy = y + dy - 1;
                    if ((unsigned)yy >= 28u) continue;
                    #pragma unroll
                    for (int dx = 0; dx < 3; ++dx) {
                        int xc = xx + dx - 1;
                        if ((unsigned)xc >= 28u) continue;
                        float xv = sx[yy * 28 + xc];
                        const float* wr = w1 + (dy * 3 + dx) * 48;
                        #pragma unroll
                        for (int c = 0; c < 48; ++c) a[c] += xv * wr[c];
                    }
                }
                #pragma unroll
                for (int cb = 0; cb < 6; ++cb) {
                    half8v h;
                    #pragma unroll
                    for (int j = 0; j < 8; ++j)
                        h[j] = (_Float16)fmaxf(a[cb * 8 + j], 0.f);
                    *(half8v*)(smem + cb * CB_STRIDE + p * 16) = h;
                }
            }
        }
    }
    __syncthreads();

    // ---- per-lane constants ----
    int tap_s[14], aoff_s[14];
    #pragma unroll
    for (int s = 0; s < 14; ++s) {
        int k = s * 32 + q * 8;
        int tap = k / 48;              // constant over j in [0,8)
        int kc  = k - tap * 48;
        int ty = tap / 3, tx = tap - ty * 3;
        tap_s[s]  = tap;
        aoff_s[s] = (kc >> 3) * CB_STRIDE + (ty * 28 + tx) * 16;
    }
    const int bB = q * 768 + l15 * 16;     // B frag byte offset within an s-block
    const char* gw2 = (const char*)wpack;
    const char* gw3 = gw2 + WPACK;
    float bias2[3], bias3[3];
    #pragma unroll
    for (int nt = 0; nt < 3; ++nt) {
        bias2[nt] = b2[nt * 16 + l15];
        bias3[nt] = b3[nt * 16 + l15];
    }

    float4v acc[7][3];
    int pixb16[7], msk[7];
    #pragma unroll
    for (int mt = 0; mt < 7; ++mt) {
        int tt = wid + mt * 8;
        int p  = tt * 16 + l15;
        int y  = (p * 9363) >> 18;             // p/28 (valid p<=895)
        int x2 = p - y * 28;
        pixb16[mt] = (p - 29) * 16;
        unsigned my0 = ((unsigned)(y - 1) < 28u) ? 0x007u : 0u;
        unsigned my1 = ((unsigned)(y    ) < 28u) ? 0x038u : 0u;
        unsigned my2 = ((unsigned)(y + 1) < 28u) ? 0x1C0u : 0u;
        unsigned mx0 = ((unsigned)(x2 - 1) < 28u) ? 0x049u : 0u;
        unsigned mx1 = ((unsigned)(x2    ) < 28u) ? 0x092u : 0u;
        unsigned mx2 = ((unsigned)(x2 + 1) < 28u) ? 0x124u : 0u;
        msk[mt] = (int)((my0 | my1 | my2) & (mx0 | mx1 | mx2));
        if (tt >= 49) msk[mt] = 0;             // pad tiles -> zero page only
        #pragma unroll
        for (int nt = 0; nt < 3; ++nt)
            acc[mt][nt] = (float4v){bias2[nt], bias2[nt], bias2[nt], bias2[nt]};
    }

    // ---- conv2 ----
    KLOOP(gw2)

    __syncthreads();                           // conv1-act reads done

    // conv2 output (ReLU, fp16) -> act region
    #pragma unroll
    for (int mt = 0; mt < 7; ++mt) {
        int tt = wid + mt * 8;
        if (tt >= 49) continue;
        #pragma unroll
        for (int nt = 0; nt < 3; ++nt) {
            int c = nt * 16 + l15;
            char* base = smem + (c >> 3) * CB_STRIDE + (c & 7) * 2;
            #pragma unroll
            for (int r = 0; r < 4; ++r) {
                int p = tt * 16 + q * 4 + r;
                *(unsigned short*)(base + p * 16) = f2h(fmaxf(acc[mt][nt][r], 0.f));
            }
        }
    }
    __syncthreads();                           // conv2 act visible

    #pragma unroll
    for (int mt = 0; mt < 7; ++mt)
        #pragma unroll
        for (int nt = 0; nt < 3; ++nt)
            acc[mt][nt] = (float4v){bias3[nt], bias3[nt], bias3[nt], bias3[nt]};

    // ---- conv3 ----
    KLOOP(gw3)

    // ---- fused ReLU + global-avg-pool + BN1 ----
    float ps0 = 0.f, ps1 = 0.f, ps2 = 0.f;
    #pragma unroll
    for (int mt = 0; mt < 7; ++mt) {
        int tt = wid + mt * 8;
        if (tt >= 49) continue;
        #pragma unroll
        for (int r = 0; r < 4; ++r) {
            ps0 += fmaxf(acc[mt][0][r], 0.f);
            ps1 += fmaxf(acc[mt][1][r], 0.f);
            ps2 += fmaxf(acc[mt][2][r], 0.f);
        }
    }
    ps0 += __shfl_xor(ps0, 16); ps0 += __shfl_xor(ps0, 32);
    ps1 += __shfl_xor(ps1, 16); ps1 += __shfl_xor(ps1, 32);
    ps2 += __shfl_xor(ps2, 16); ps2 += __shfl_xor(ps2, 32);
    __syncthreads();                           // act region dead; alias as reduce buf
    float* sRed = (float*)smem;
    if (lane < 16) {
        sRed[wid * 48 + l15]      = ps0;
        sRed[wid * 48 + 16 + l15] = ps1;
        sRed[wid * 48 + 32 + l15] = ps2;
    }
    __syncthreads();
    if (tid < 48) {
        float s = 0.f;
        #pragma unroll
        for (int wv = 0; wv < 8; ++wv) s += sRed[wv * 48 + tid];
        float r  = rsqrtf(bn_v[tid] + EPSV);
        float sc = r * bn_g[tid] * (1.0f / 784.0f);
        float sh = bn_b[tid] - bn_m[tid] * r * bn_g[tid];
        feats[(size_t)n * 48 + tid] = s * sc + sh;
    }
}

// ---------------------------------------------------------------------------
// Kernel 2: LSTM + BN2 + dense head. One wave per batch element.
// Lane l: half = l>>5 (K-half), gu = l&31 -> gate g = gu>>3, unit u = gu&7.
// Gate weights held in registers (28 per lane); z broadcast from LDS.
// ---------------------------------------------------------------------------
__global__ __launch_bounds__(64) void lstm_kernel(
    const float* __restrict__ feats,
    const float* __restrict__ wf, const float* __restrict__ bfv,
    const float* __restrict__ wi1, const float* __restrict__ bi1,
    const float* __restrict__ wi2, const float* __restrict__ bi2,
    const float* __restrict__ wo, const float* __restrict__ bov,
    const float* __restrict__ g2, const float* __restrict__ b2v,
    const float* __restrict__ m2, const float* __restrict__ v2,
    const float* __restrict__ w_out, const float* __restrict__ b_out,
    float* __restrict__ out)
{
    __shared__ float sZ[56];     // [0,48) = x_t, [48,56) = h
    __shared__ float sG[32];     // gates f,i,g,o
    __shared__ float sS[8];
    __shared__ float sKs;

    int tid = threadIdx.x;
    int b = blockIdx.x;
    int gu = tid & 31, g = gu >> 3, u = gu & 7, half = tid >> 5;

    const float* wsrc = (g == 0) ? wf : (g == 1) ? wi1 : (g == 2) ? wi2 : wo;
    float wreg[28];
    #pragma unroll
    for (int j = 0; j < 28; ++j) wreg[j] = wsrc[(half * 28 + j) * 8 + u];
    float bias = ((g == 0) ? bfv : (g == 1) ? bi1 : (g == 2) ? bi2 : bov)[u];

    if (tid < 8) {
        float r = rsqrtf(v2[tid] + EPSV);
        sS[tid] = r * g2[tid] * w_out[tid];
        sZ[48 + tid] = 0.f;
    }
    if (tid == 0) {
        float k = b_out[0];
        for (int uu = 0; uu < 8; ++uu) {
            float r = rsqrtf(v2[uu] + EPSV);
            k += (b2v[uu] - m2[uu] * r * g2[uu]) * w_out[uu];
        }
        sKs = k;
    }

    float c = 0.f;
    const float* fb = feats + (size_t)b * T_ * 48;

    for (int t = 0; t < T_; ++t) {
        if (tid < 48) sZ[tid] = fb[t * 48 + tid];
        __syncthreads();

        float a = 0.f;
        #pragma unroll
        for (int j = 0; j < 28; ++j) a += sZ[half * 28 + j] * wreg[j];
        a += __shfl_xor(a, 32);
        a += bias;
        float v;
        if (g == 2) { float e = __expf(2.f * a); v = 1.f - 2.f / (e + 1.f); }
        else        { v = 1.f / (1.f + __expf(-a)); }
        if (tid < 32) sG[gu] = v;
        __syncthreads();

        if (tid < 8) {
            c = sG[tid] * c + sG[8 + tid] * sG[16 + tid];
            float e = __expf(2.f * c);
            float h = sG[24 + tid] * (1.f - 2.f / (e + 1.f));
            sZ[48 + tid] = h;
            float contrib = h * sS[tid];
            contrib += __shfl_xor(contrib, 1);
            contrib += __shfl_xor(contrib, 2);
            contrib += __shfl_xor(contrib, 4);
            if (tid == 0) out[b * T_ + t] = contrib + sKs;
        }
        __syncthreads();
    }
}

// ---------------------------------------------------------------------------
extern "C" void kernel_launch(void* const* d_in, const int* in_sizes, int n_in,
                              void* d_out, int out_size, void* d_ws, size_t ws_size,
                              hipStream_t stream)
{
    const float* x    = (const float*)d_in[0];
    const float* w1   = (const float*)d_in[1];
    const float* b1   = (const float*)d_in[2];
    const float* w2   = (const float*)d_in[3];
    const float* b2   = (const float*)d_in[4];
    const float* w3   = (const float*)d_in[5];
    const float* b3   = (const float*)d_in[6];
    const float* bn1g = (const float*)d_in[7];
    const float* bn1b = (const float*)d_in[8];
    const float* bn1m = (const float*)d_in[9];
    const float* bn1v = (const float*)d_in[10];
    const float* wf   = (const float*)d_in[11];
    const float* bf   = (const float*)d_in[12];
    const float* wi1  = (const float*)d_in[13];
    const float* bi1  = (const float*)d_in[14];
    const float* wi2  = (const float*)d_in[15];
    const float* bi2  = (const float*)d_in[16];
    const float* wo   = (const float*)d_in[17];
    const float* bo   = (const float*)d_in[18];
    const float* bn2g = (const float*)d_in[19];
    const float* bn2b = (const float*)d_in[20];
    const float* bn2m = (const float*)d_in[21];
    const float* bn2v = (const float*)d_in[22];
    const float* wout = (const float*)d_in[23];
    const float* bout = (const float*)d_in[24];

    unsigned short* wpack = (unsigned short*)d_ws;            // 2*43008 B
    float* feats = (float*)((char*)d_ws + 2 * WPACK);         // 1024*48 fp32
    const size_t need = 2 * WPACK + (size_t)NFRM * 48 * 4;
    if (ws_size < need) return;

    pack_weights<<<168, 256, 0, stream>>>(w2, w3, wpack);
    fused_cnn<<<NFRM, 512, 0, stream>>>(x, w1, b1, b2, b3, wpack, feats,
                                        bn1g, bn1b, bn1m, bn1v);
    lstm_kernel<<<B_, 64, 0, stream>>>(feats, wf, bf, wi1, bi1, wi2, bi2, wo, bo,
                                       bn2g, bn2b, bn2m, bn2v, wout, bout,
                                       (float*)d_out);
}

// Round 6
// 109.946 us; speedup vs baseline: 2.1964x; 2.1964x over previous
//
#include <hip/hip_runtime.h>
#include <stdint.h>

#define B_ 32
#define T_ 32
#define NPIX 784
#define NFRM 1024
#define EPSV 1e-3f

typedef __attribute__((ext_vector_type(8))) _Float16 half8v;
typedef __attribute__((ext_vector_type(4))) float float4v;

// ---- LDS map (bytes) ----
// act region [0, 75456)       : fp16 acts, 6 cb * 12576 B; chunk = (cb, pixel) 16B
// zero page  [75456, 75472)
// x region   [75472, 78608)   : raw frame fp32 (784*4)
#define CB_STRIDE 12576
#define ZERO_OFF  75456
#define X_OFF     75472
#define LDS_TOT   78608              // <= 80 KiB -> 2 blocks/CU (with VGPR <= 128)
#define WPACK     43008              // bytes per conv weight pack

__device__ __forceinline__ unsigned short f2h(float f) {
    union { _Float16 h; unsigned short u; } cv; cv.h = (_Float16)f; return cv.u;
}

// ---------------------------------------------------------------------------
// Kernel 0: pack w2/w3 as fp16 in MFMA-B fragment order [s][q][co][j].
// k = s*32 + q*8 + j = tap*48 + cin ; k >= 432 zero-padded.
// ---------------------------------------------------------------------------
__global__ __launch_bounds__(256) void pack_weights(
    const float* __restrict__ w2, const float* __restrict__ w3,
    unsigned short* __restrict__ out)
{
    int idx = blockIdx.x * 256 + threadIdx.x;     // 0 .. 43007
    int conv = idx / 21504;
    int r = idx - conv * 21504;
    const float* w = conv ? w3 : w2;
    int s  = r / 1536;
    int r2 = r - s * 1536;
    int q  = r2 / 384;
    int r3 = r2 - q * 384;
    int co = r3 >> 3, j = r3 & 7;
    int k  = s * 32 + q * 8 + j;
    unsigned short v = 0;
    if (k < 432) v = f2h(w[k * 48 + co]);
    out[idx] = v;
}

// ---------------------------------------------------------------------------
// Fused conv1 + conv2 + conv3 (fp16 MFMA) + ReLU + avgpool + BN1.
// One block = one frame; 512 threads = 8 waves; wave w owns M-tiles tt=w+8*mt.
// B-operand fragments load straight from global (L1/L2-hot, same for all blocks).
// mt=6 (tiles 48..55) is real only for wave 0 -> other waves branch over it.
// __launch_bounds__ 2nd arg == blocks/CU on this toolchain (R4 post-mortem:
// (512,4) forced VGPR=64 and spilled); (512,2) -> VGPR cap 128 = natural alloc.
// ---------------------------------------------------------------------------
#define KLOOP(GW)                                                              \
    _Pragma("unroll")                                                          \
    for (int s = 0; s < 14; ++s) {                                             \
        const char* wb = (GW) + bB + s * 3072;                                 \
        half8v bv0 = *(const half8v*)(wb);                                     \
        half8v bv1 = *(const half8v*)(wb + 256);                               \
        half8v bv2 = *(const half8v*)(wb + 512);                               \
        _Pragma("unroll")                                                      \
        for (int mt = 0; mt < 7; ++mt) {                                       \
            if (mt < 6 || wid == 0) {                                          \
                int ad = pixb16[mt] + aoff_s[s];                               \
                ad = ((msk[mt] >> tap_s[s]) & 1) ? ad : ZERO_OFF;              \
                half8v a = *(const half8v*)(smem + ad);                        \
                acc[mt][0] = __builtin_amdgcn_mfma_f32_16x16x32_f16(a, bv0, acc[mt][0], 0, 0, 0); \
                acc[mt][1] = __builtin_amdgcn_mfma_f32_16x16x32_f16(a, bv1, acc[mt][1], 0, 0, 0); \
                acc[mt][2] = __builtin_amdgcn_mfma_f32_16x16x32_f16(a, bv2, acc[mt][2], 0, 0, 0); \
            }                                                                  \
        }                                                                      \
    }

__global__ __launch_bounds__(512, 2) void fused_cnn(
    const float* __restrict__ x,              // [NFRM][784] fp32
    const float* __restrict__ w1, const float* __restrict__ b1,
    const float* __restrict__ b2, const float* __restrict__ b3,
    const unsigned short* __restrict__ wpack, // [2][21504] halfs (frag order)
    float* __restrict__ feats,                // [NFRM][48]
    const float* __restrict__ bn_g, const float* __restrict__ bn_b,
    const float* __restrict__ bn_m, const float* __restrict__ bn_v)
{
    __shared__ __align__(16) char smem[LDS_TOT];
    const int tid = threadIdx.x;
    const int n = blockIdx.x;
    const int lane = tid & 63, wid = tid >> 6;
    const int l15 = lane & 15, q = lane >> 4;

    // zero page + stage raw frame
    if (tid < 4) *(unsigned int*)(smem + ZERO_OFF + tid * 4) = 0;
    {
        const float* xf = x + (size_t)n * NPIX;
        float* sx = (float*)(smem + X_OFF);
        for (int i = tid; i < NPIX; i += 512) sx[i] = xf[i];
    }
    __syncthreads();

    // ---- conv1 (1->48) on VALU, fp16 chunks into act region ----
    {
        const float* sx = (const float*)(smem + X_OFF);
        for (int rnd = 0; rnd < 2; ++rnd) {
            int p = tid + rnd * 512;
            if (p < NPIX) {
                int y = p / 28, xx = p % 28;
                float a[48];
                #pragma unroll
                for (int c = 0; c < 48; ++c) a[c] = b1[c];
                #pragma unroll
                for (int dy = 0; dy < 3; ++dy) {
                    int yy = y + dy - 1;
                    if ((unsigned)yy >= 28u) continue;
                    #pragma unroll
                    for (int dx = 0; dx < 3; ++dx) {
                        int xc = xx + dx - 1;
                        if ((unsigned)xc >= 28u) continue;
                        float xv = sx[yy * 28 + xc];
                        const float* wr = w1 + (dy * 3 + dx) * 48;
                        #pragma unroll
                        for (int c = 0; c < 48; ++c) a[c] += xv * wr[c];
                    }
                }
                #pragma unroll
                for (int cb = 0; cb < 6; ++cb) {
                    half8v h;
                    #pragma unroll
                    for (int j = 0; j < 8; ++j)
                        h[j] = (_Float16)fmaxf(a[cb * 8 + j], 0.f);
                    *(half8v*)(smem + cb * CB_STRIDE + p * 16) = h;
                }
            }
        }
    }
    __syncthreads();

    // ---- per-lane constants ----
    int tap_s[14], aoff_s[14];
    #pragma unroll
    for (int s = 0; s < 14; ++s) {
        int k = s * 32 + q * 8;
        int tap = k / 48;              // constant over j in [0,8)
        int kc  = k - tap * 48;
        int ty = tap / 3, tx = tap - ty * 3;
        tap_s[s]  = tap;
        aoff_s[s] = (kc >> 3) * CB_STRIDE + (ty * 28 + tx) * 16;
    }
    const int bB = q * 768 + l15 * 16;     // B frag byte offset within an s-block
    const char* gw2 = (const char*)wpack;
    const char* gw3 = gw2 + WPACK;
    float bias2[3], bias3[3];
    #pragma unroll
    for (int nt = 0; nt < 3; ++nt) {
        bias2[nt] = b2[nt * 16 + l15];
        bias3[nt] = b3[nt * 16 + l15];
    }

    float4v acc[7][3];
    int pixb16[7], msk[7];
    #pragma unroll
    for (int mt = 0; mt < 7; ++mt) {
        int tt = wid + mt * 8;
        int p  = tt * 16 + l15;
        int y  = (p * 9363) >> 18;             // p/28 (valid p<=895)
        int x2 = p - y * 28;
        pixb16[mt] = (p - 29) * 16;
        unsigned my0 = ((unsigned)(y - 1) < 28u) ? 0x007u : 0u;
        unsigned my1 = ((unsigned)(y    ) < 28u) ? 0x038u : 0u;
        unsigned my2 = ((unsigned)(y + 1) < 28u) ? 0x1C0u : 0u;
        unsigned mx0 = ((unsigned)(x2 - 1) < 28u) ? 0x049u : 0u;
        unsigned mx1 = ((unsigned)(x2    ) < 28u) ? 0x092u : 0u;
        unsigned mx2 = ((unsigned)(x2 + 1) < 28u) ? 0x124u : 0u;
        msk[mt] = (int)((my0 | my1 | my2) & (mx0 | mx1 | mx2));
        if (tt >= 49) msk[mt] = 0;             // pad tiles -> zero page only
        #pragma unroll
        for (int nt = 0; nt < 3; ++nt)
            acc[mt][nt] = (float4v){bias2[nt], bias2[nt], bias2[nt], bias2[nt]};
    }

    // ---- conv2 ----
    KLOOP(gw2)

    __syncthreads();                           // conv1-act reads done

    // conv2 output (ReLU, fp16) -> act region
    #pragma unroll
    for (int mt = 0; mt < 7; ++mt) {
        int tt = wid + mt * 8;
        if (tt >= 49) continue;
        #pragma unroll
        for (int nt = 0; nt < 3; ++nt) {
            int c = nt * 16 + l15;
            char* base = smem + (c >> 3) * CB_STRIDE + (c & 7) * 2;
            #pragma unroll
            for (int r = 0; r < 4; ++r) {
                int p = tt * 16 + q * 4 + r;
                *(unsigned short*)(base + p * 16) = f2h(fmaxf(acc[mt][nt][r], 0.f));
            }
        }
    }
    __syncthreads();                           // conv2 act visible

    #pragma unroll
    for (int mt = 0; mt < 7; ++mt)
        #pragma unroll
        for (int nt = 0; nt < 3; ++nt)
            acc[mt][nt] = (float4v){bias3[nt], bias3[nt], bias3[nt], bias3[nt]};

    // ---- conv3 ----
    KLOOP(gw3)

    // ---- fused ReLU + global-avg-pool + BN1 ----
    float ps0 = 0.f, ps1 = 0.f, ps2 = 0.f;
    #pragma unroll
    for (int mt = 0; mt < 7; ++mt) {
        int tt = wid + mt * 8;
        if (tt >= 49) continue;
        #pragma unroll
        for (int r = 0; r < 4; ++r) {
            ps0 += fmaxf(acc[mt][0][r], 0.f);
            ps1 += fmaxf(acc[mt][1][r], 0.f);
            ps2 += fmaxf(acc[mt][2][r], 0.f);
        }
    }
    ps0 += __shfl_xor(ps0, 16); ps0 += __shfl_xor(ps0, 32);
    ps1 += __shfl_xor(ps1, 16); ps1 += __shfl_xor(ps1, 32);
    ps2 += __shfl_xor(ps2, 16); ps2 += __shfl_xor(ps2, 32);
    __syncthreads();                           // act region dead; alias as reduce buf
    float* sRed = (float*)smem;
    if (lane < 16) {
        sRed[wid * 48 + l15]      = ps0;
        sRed[wid * 48 + 16 + l15] = ps1;
        sRed[wid * 48 + 32 + l15] = ps2;
    }
    __syncthreads();
    if (tid < 48) {
        float s = 0.f;
        #pragma unroll
        for (int wv = 0; wv < 8; ++wv) s += sRed[wv * 48 + tid];
        float r  = rsqrtf(bn_v[tid] + EPSV);
        float sc = r * bn_g[tid] * (1.0f / 784.0f);
        float sh = bn_b[tid] - bn_m[tid] * r * bn_g[tid];
        feats[(size_t)n * 48 + tid] = s * sc + sh;
    }
}

// ---------------------------------------------------------------------------
// Kernel 2: LSTM + BN2 + dense head. One wave per batch element.
// Lane l: half = l>>5 (K-half), gu = l&31 -> gate g = gu>>3, unit u = gu&7.
// Gate weights held in registers (28 per lane); z broadcast from LDS.
// ---------------------------------------------------------------------------
__global__ __launch_bounds__(64) void lstm_kernel(
    const float* __restrict__ feats,
    const float* __restrict__ wf, const float* __restrict__ bfv,
    const float* __restrict__ wi1, const float* __restrict__ bi1,
    const float* __restrict__ wi2, const float* __restrict__ bi2,
    const float* __restrict__ wo, const float* __restrict__ bov,
    const float* __restrict__ g2, const float* __restrict__ b2v,
    const float* __restrict__ m2, const float* __restrict__ v2,
    const float* __restrict__ w_out, const float* __restrict__ b_out,
    float* __restrict__ out)
{
    __shared__ float sZ[56];     // [0,48) = x_t, [48,56) = h
    __shared__ float sG[32];     // gates f,i,g,o
    __shared__ float sS[8];
    __shared__ float sKs;

    int tid = threadIdx.x;
    int b = blockIdx.x;
    int gu = tid & 31, g = gu >> 3, u = gu & 7, half = tid >> 5;

    const float* wsrc = (g == 0) ? wf : (g == 1) ? wi1 : (g == 2) ? wi2 : wo;
    float wreg[28];
    #pragma unroll
    for (int j = 0; j < 28; ++j) wreg[j] = wsrc[(half * 28 + j) * 8 + u];
    float bias = ((g == 0) ? bfv : (g == 1) ? bi1 : (g == 2) ? bi2 : bov)[u];

    if (tid < 8) {
        float r = rsqrtf(v2[tid] + EPSV);
        sS[tid] = r * g2[tid] * w_out[tid];
        sZ[48 + tid] = 0.f;
    }
    if (tid == 0) {
        float k = b_out[0];
        for (int uu = 0; uu < 8; ++uu) {
            float r = rsqrtf(v2[uu] + EPSV);
            k += (b2v[uu] - m2[uu] * r * g2[uu]) * w_out[uu];
        }
        sKs = k;
    }

    float c = 0.f;
    const float* fb = feats + (size_t)b * T_ * 48;

    for (int t = 0; t < T_; ++t) {
        if (tid < 48) sZ[tid] = fb[t * 48 + tid];
        __syncthreads();

        float a = 0.f;
        #pragma unroll
        for (int j = 0; j < 28; ++j) a += sZ[half * 28 + j] * wreg[j];
        a += __shfl_xor(a, 32);
        a += bias;
        float v;
        if (g == 2) { float e = __expf(2.f * a); v = 1.f - 2.f / (e + 1.f); }
        else        { v = 1.f / (1.f + __expf(-a)); }
        if (tid < 32) sG[gu] = v;
        __syncthreads();

        if (tid < 8) {
            c = sG[tid] * c + sG[8 + tid] * sG[16 + tid];
            float e = __expf(2.f * c);
            float h = sG[24 + tid] * (1.f - 2.f / (e + 1.f));
            sZ[48 + tid] = h;
            float contrib = h * sS[tid];
            contrib += __shfl_xor(contrib, 1);
            contrib += __shfl_xor(contrib, 2);
            contrib += __shfl_xor(contrib, 4);
            if (tid == 0) out[b * T_ + t] = contrib + sKs;
        }
        __syncthreads();
    }
}

// ---------------------------------------------------------------------------
extern "C" void kernel_launch(void* const* d_in, const int* in_sizes, int n_in,
                              void* d_out, int out_size, void* d_ws, size_t ws_size,
                              hipStream_t stream)
{
    const float* x    = (const float*)d_in[0];
    const float* w1   = (const float*)d_in[1];
    const float* b1   = (const float*)d_in[2];
    const float* w2   = (const float*)d_in[3];
    const float* b2   = (const float*)d_in[4];
    const float* w3   = (const float*)d_in[5];
    const float* b3   = (const float*)d_in[6];
    const float* bn1g = (const float*)d_in[7];
    const float* bn1b = (const float*)d_in[8];
    const float* bn1m = (const float*)d_in[9];
    const float* bn1v = (const float*)d_in[10];
    const float* wf   = (const float*)d_in[11];
    const float* bf   = (const float*)d_in[12];
    const float* wi1  = (const float*)d_in[13];
    const float* bi1  = (const float*)d_in[14];
    const float* wi2  = (const float*)d_in[15];
    const float* bi2  = (const float*)d_in[16];
    const float* wo   = (const float*)d_in[17];
    const float* bo   = (const float*)d_in[18];
    const float* bn2g = (const float*)d_in[19];
    const float* bn2b = (const float*)d_in[20];
    const float* bn2m = (const float*)d_in[21];
    const float* bn2v = (const float*)d_in[22];
    const float* wout = (const float*)d_in[23];
    const float* bout = (const float*)d_in[24];

    unsigned short* wpack = (unsigned short*)d_ws;            // 2*43008 B
    float* feats = (float*)((char*)d_ws + 2 * WPACK);         // 1024*48 fp32
    const size_t need = 2 * WPACK + (size_t)NFRM * 48 * 4;
    if (ws_size < need) return;

    pack_weights<<<168, 256, 0, stream>>>(w2, w3, wpack);
    fused_cnn<<<NFRM, 512, 0, stream>>>(x, w1, b1, b2, b3, wpack, feats,
                                        bn1g, bn1b, bn1m, bn1v);
    lstm_kernel<<<B_, 64, 0, stream>>>(feats, wf, bf, wi1, bi1, wi2, bi2, wo, bo,
                                       bn2g, bn2b, bn2m, bn2v, wout, bout,
                                       (float*)d_out);
}